// Round 1
// baseline (7929.185 us; speedup 1.0000x reference)
//
#include <hip/hip_runtime.h>

typedef __attribute__((ext_vector_type(8))) short bf16x8_t;
typedef __attribute__((ext_vector_type(4))) float f32x4_t;
typedef __attribute__((ext_vector_type(4))) int i32x4_t;

__device__ __forceinline__ unsigned short f2b(float f) {
  unsigned int u = __builtin_bit_cast(unsigned int, f);
  u += 0x7fffu + ((u >> 16) & 1u);
  return (unsigned short)(u >> 16);
}
__device__ __forceinline__ float b2f(unsigned short h) {
  unsigned int u = ((unsigned int)h) << 16;
  return __builtin_bit_cast(float, u);
}

// ---------------- transpose+convert: in f32 [K][N] -> out bf16 [Npad][K] ----------------
__global__ void transpose_w(const float* __restrict__ in, unsigned short* __restrict__ out,
                            int K, int N, int Npad, long inBatch, long outBatch)
{
  __shared__ float tile[32][33];
  const int bz = blockIdx.z;
  in += (long)bz * inBatch;
  out += (long)bz * outBatch;
  const int k0 = blockIdx.x * 32, n0 = blockIdx.y * 32;
  const int tx = threadIdx.x, ty = threadIdx.y;  // 32 x 8
#pragma unroll
  for (int i = 0; i < 32; i += 8) {
    const int k = k0 + ty + i, n = n0 + tx;
    tile[ty + i][tx] = (k < K && n < N) ? in[(long)k * N + n] : 0.f;
  }
  __syncthreads();
#pragma unroll
  for (int i = 0; i < 32; i += 8) {
    const int n = n0 + ty + i, k = k0 + tx;
    if (n < Npad && k < K) out[(long)n * K + k] = f2b(tile[tx][ty + i]);
  }
}

__global__ void build_bqkv(const float* __restrict__ bq, const float* __restrict__ bk,
                           const float* __restrict__ bv, float* __restrict__ out)
{
  const int i = blockIdx.x * 256 + threadIdx.x;
  if (i >= 12 * 2304) return;
  const int l = i / 2304, j = i % 2304;
  float v;
  if (j < 768) v = bq[l * 768 + j];
  else if (j < 1536) v = bk[l * 768 + j - 768];
  else v = bv[l * 768 + j - 1536];
  out[i] = v;
}
__global__ void build_clsb(const float* __restrict__ cb, float* __restrict__ out)
{
  const int i = blockIdx.x * 256 + threadIdx.x;
  if (i < 21248) out[i] = (i < 21128) ? cb[i] : 0.f;
}

// ---------------- GEMM: C[M][N] = A[M][K] (bf16) x Bt[N][K] (bf16) ----------------
// epilogue: +bias[n], gelu (flags&1), +resid (f32), stores Cf (f32) and/or Cb (bf16)
#define TM 128
#define TN 128
#define BK 64
#define LDK 72

__global__ __launch_bounds__(256, 2)
void gemm_bf16(const unsigned short* __restrict__ A,
               const unsigned short* __restrict__ Bt,
               const float* __restrict__ bias,
               const float* __restrict__ resid,
               float* __restrict__ Cf,
               unsigned short* __restrict__ Cb,
               int M, int N, int K, int ldc, int flags)
{
  __shared__ unsigned short lA[TM * LDK];
  __shared__ unsigned short lB[TN * LDK];
  const int tid = threadIdx.x;
  const int wave = tid >> 6, lane = tid & 63;
  const int quad = lane >> 4, lidx = lane & 15;
  const int m0 = blockIdx.x * TM, n0 = blockIdx.y * TN;
  const int wm = (wave >> 1) * 64, wn = (wave & 1) * 64;
  f32x4_t acc[4][4] = {};
  const int ar = tid >> 3, ac = (tid & 7) * 8;
  const unsigned short* Ag = A + (long)(m0 + ar) * K + ac;
  const unsigned short* Bg = Bt + (long)(n0 + ar) * K + ac;
  for (int k0 = 0; k0 < K; k0 += BK) {
#pragma unroll
    for (int i = 0; i < 4; i++) {
      *(i32x4_t*)&lA[(ar + i * 32) * LDK + ac] = *(const i32x4_t*)(Ag + (long)i * 32 * K + k0);
      *(i32x4_t*)&lB[(ar + i * 32) * LDK + ac] = *(const i32x4_t*)(Bg + (long)i * 32 * K + k0);
    }
    __syncthreads();
#pragma unroll
    for (int kk = 0; kk < 2; kk++) {
      bf16x8_t af[4], bf[4];
#pragma unroll
      for (int t = 0; t < 4; t++) {
        af[t] = *(const bf16x8_t*)&lA[(wm + t * 16 + lidx) * LDK + kk * 32 + quad * 8];
        bf[t] = *(const bf16x8_t*)&lB[(wn + t * 16 + lidx) * LDK + kk * 32 + quad * 8];
      }
#pragma unroll
      for (int mt = 0; mt < 4; mt++)
#pragma unroll
        for (int nt = 0; nt < 4; nt++)
          acc[mt][nt] = __builtin_amdgcn_mfma_f32_16x16x32_bf16(af[mt], bf[nt], acc[mt][nt], 0, 0, 0);
    }
    __syncthreads();
  }
#pragma unroll
  for (int mt = 0; mt < 4; mt++) {
#pragma unroll
    for (int nt = 0; nt < 4; nt++) {
#pragma unroll
      for (int r = 0; r < 4; r++) {
        const int row = m0 + wm + mt * 16 + quad * 4 + r;
        const int col = n0 + wn + nt * 16 + lidx;
        float v = acc[mt][nt][r];
        if (bias) v += bias[col];
        if (flags & 1) v = 0.5f * v * (1.0f + erff(v * 0.70710678118f));
        const long o = (long)row * ldc + col;
        if (resid) v += resid[o];
        if (Cf) Cf[o] = v;
        if (Cb) Cb[o] = f2b(v);
      }
    }
  }
}

// ---------------- attention: per (qchunk, head, batch) block ----------------
__global__ __launch_bounds__(256, 2)
void attn_kernel(const unsigned short* __restrict__ qkv,   // [B*S][2304] = Q|K|V
                 unsigned short* __restrict__ ctx,         // [B*S][768]
                 const int* __restrict__ s1p)
{
  __shared__ unsigned short sh[32768];   // 64 KB: K [0,16384), V [16384,32768); P aliases K
  unsigned short* lK = sh;
  unsigned short* lV = sh + 16384;
  unsigned short* lP = sh;
  const int s1 = s1p[0];
  const int qc = blockIdx.x, h = blockIdx.y, b = blockIdx.z;
  const int tid = threadIdx.x;
  const int wave = tid >> 6, lane = tid & 63;
  const int quad = lane >> 4, lidx = lane & 15;
  const long tokbase = (long)b * 256 * 2304 + h * 64;

  {  // stage K,V with xor-swizzled 16B chunks (8 chunks per 64-wide row)
    const int kr = tid >> 3, c8 = tid & 7;
#pragma unroll
    for (int i = 0; i < 8; i++) {
      const int key = kr + i * 32;
      const unsigned short* src = qkv + tokbase + (long)key * 2304 + c8 * 8;
      const int sw = (c8 ^ (key & 7)) << 3;
      *(i32x4_t*)&lK[key * 64 + sw] = *(const i32x4_t*)(src + 768);
      *(i32x4_t*)&lV[key * 64 + sw] = *(const i32x4_t*)(src + 1536);
    }
  }
  bf16x8_t aq[2];
  {
    const int q = qc * 64 + wave * 16 + lidx;
    const unsigned short* qp = qkv + tokbase + (long)q * 2304;
    aq[0] = *(const bf16x8_t*)(qp + quad * 8);
    aq[1] = *(const bf16x8_t*)(qp + 32 + quad * 8);
  }
  __syncthreads();
  // QK^T: scores [16 q rows of this wave] x [256 keys]
  f32x4_t sc[16] = {};
#pragma unroll
  for (int kk = 0; kk < 2; kk++) {
#pragma unroll
    for (int nt = 0; nt < 16; nt++) {
      const int key = nt * 16 + lidx;
      const int ch = kk * 4 + quad;
      bf16x8_t bk = *(const bf16x8_t*)&lK[key * 64 + ((ch ^ (key & 7)) << 3)];
      sc[nt] = __builtin_amdgcn_mfma_f32_16x16x32_bf16(aq[kk], bk, sc[nt], 0, 0, 0);
    }
  }
  __syncthreads();   // all K reads done before P overwrites the same LDS
  const float scale = 0.125f;
  float rsum[4];
#pragma unroll
  for (int r = 0; r < 4; r++) {
    const int ql = wave * 16 + quad * 4 + r;
    const int q = qc * 64 + ql;
    float sv[16], m = -1e30f;
#pragma unroll
    for (int nt = 0; nt < 16; nt++) {
      const int key = nt * 16 + lidx;
      const float s = sc[nt][r] * scale + ((key < s1 || key <= q) ? 0.f : -1e9f);
      sv[nt] = s;
      m = fmaxf(m, s);
    }
#pragma unroll
    for (int o = 1; o < 16; o <<= 1) m = fmaxf(m, __shfl_xor(m, o, 16));
    float sum = 0.f;
#pragma unroll
    for (int nt = 0; nt < 16; nt++) {
      const float p = __expf(sv[nt] - m);
      sum += p;
      const int key = nt * 16 + lidx;
      lP[ql * 256 + ((((key >> 3) ^ (ql & 7))) << 3) + (key & 7)] = f2b(p);
    }
#pragma unroll
    for (int o = 1; o < 16; o <<= 1) sum += __shfl_xor(sum, o, 16);
    rsum[r] = sum;
  }
  __syncthreads();
  // PV: ctx[16 q][64 d] += P[16][256] x V[256][64]
  f32x4_t o4[4] = {};
#pragma unroll
  for (int kk = 0; kk < 8; kk++) {
    const int row = wave * 16 + lidx;
    const int ch = kk * 4 + quad;
    bf16x8_t ap = *(const bf16x8_t*)&lP[row * 256 + ((ch ^ (row & 7)) << 3)];
#pragma unroll
    for (int nt = 0; nt < 4; nt++) {
      bf16x8_t bv;
#pragma unroll
      for (int j = 0; j < 8; j++) {
        const int key = kk * 32 + quad * 8 + j;
        const int d = nt * 16 + lidx;
        bv[j] = (short)lV[key * 64 + (((d >> 3) ^ (key & 7)) << 3) + (d & 7)];
      }
      o4[nt] = __builtin_amdgcn_mfma_f32_16x16x32_bf16(ap, bv, o4[nt], 0, 0, 0);
    }
  }
#pragma unroll
  for (int nt = 0; nt < 4; nt++) {
#pragma unroll
    for (int r = 0; r < 4; r++) {
      const int q = qc * 64 + wave * 16 + quad * 4 + r;
      const int d = nt * 16 + lidx;
      ctx[(long)(b * 256 + q) * 768 + h * 64 + d] = f2b(o4[nt][r] / rsum[r]);
    }
  }
}

// ---------------- LayerNorm over H=768; writes f32 + bf16 ----------------
__global__ void ln_kernel(const float* __restrict__ in, const float* __restrict__ g,
                          const float* __restrict__ be, float* __restrict__ o32,
                          unsigned short* __restrict__ ob)
{
  __shared__ float sb1[4], sb2[4];
  const int row = blockIdx.x, tid = threadIdx.x;
  const float* x = in + (long)row * 768;
  float v[3], s = 0.f, ss = 0.f;
#pragma unroll
  for (int i = 0; i < 3; i++) { v[i] = x[tid + i * 256]; s += v[i]; ss += v[i] * v[i]; }
#pragma unroll
  for (int o = 32; o > 0; o >>= 1) { s += __shfl_down(s, o); ss += __shfl_down(ss, o); }
  if ((tid & 63) == 0) { sb1[tid >> 6] = s; sb2[tid >> 6] = ss; }
  __syncthreads();
  s = sb1[0] + sb1[1] + sb1[2] + sb1[3];
  ss = sb2[0] + sb2[1] + sb2[2] + sb2[3];
  const float mean = s * (1.f / 768.f);
  const float inv = rsqrtf(ss * (1.f / 768.f) - mean * mean + 1e-12f);
#pragma unroll
  for (int i = 0; i < 3; i++) {
    const int c = tid + i * 256;
    const float yv = (v[i] - mean) * inv * g[c] + be[c];
    if (o32) o32[(long)row * 768 + c] = yv;
    ob[(long)row * 768 + c] = f2b(yv);
  }
}

__global__ void embed_kernel(const int* __restrict__ xi, const float* __restrict__ we,
                             const float* __restrict__ pe, const float* __restrict__ te,
                             const float* __restrict__ g, const float* __restrict__ be,
                             float* __restrict__ o32, unsigned short* __restrict__ ob)
{
  __shared__ float sb1[4], sb2[4];
  const int row = blockIdx.x, tid = threadIdx.x;
  const int sidx = row & 255;
  const long id = xi[row];
  float v[3], s = 0.f, ss = 0.f;
#pragma unroll
  for (int i = 0; i < 3; i++) {
    const int c = tid + i * 256;
    v[i] = we[id * 768 + c] + pe[(long)sidx * 768 + c] + te[c];
    s += v[i]; ss += v[i] * v[i];
  }
#pragma unroll
  for (int o = 32; o > 0; o >>= 1) { s += __shfl_down(s, o); ss += __shfl_down(ss, o); }
  if ((tid & 63) == 0) { sb1[tid >> 6] = s; sb2[tid >> 6] = ss; }
  __syncthreads();
  s = sb1[0] + sb1[1] + sb1[2] + sb1[3];
  ss = sb2[0] + sb2[1] + sb2[2] + sb2[3];
  const float mean = s * (1.f / 768.f);
  const float inv = rsqrtf(ss * (1.f / 768.f) - mean * mean + 1e-12f);
#pragma unroll
  for (int i = 0; i < 3; i++) {
    const int c = tid + i * 256;
    const float yv = (v[i] - mean) * inv * g[c] + be[c];
    o32[(long)row * 768 + c] = yv;
    ob[(long)row * 768 + c] = f2b(yv);
  }
}

// ---------------- online log-sum-exp over classifier chunks ----------------
__global__ void loss_partial(const unsigned short* __restrict__ logits,  // [8192][nC] bf16
                             const int* __restrict__ y,
                             float* __restrict__ st,                     // [8192][3]: m, s, target_logit
                             int n0, int nC, int first)
{
  __shared__ float sb[4];
  const int row = blockIdx.x, tid = threadIdx.x;
  const unsigned short* lp = logits + (long)row * nC;
  float lv[21];
  float m = -1e30f;
  int cnt = 0;
#pragma unroll
  for (int i = 0; i < 21; i++) {
    const int c = tid + i * 256;
    if (c < nC) { lv[i] = b2f(lp[c]); m = fmaxf(m, lv[i]); cnt = i + 1; }
  }
#pragma unroll
  for (int o = 32; o > 0; o >>= 1) m = fmaxf(m, __shfl_down(m, o));
  if ((tid & 63) == 0) sb[tid >> 6] = m;
  __syncthreads();
  m = fmaxf(fmaxf(sb[0], sb[1]), fmaxf(sb[2], sb[3]));
  __syncthreads();
  float sum = 0.f;
  for (int i = 0; i < cnt; i++) sum += __expf(lv[i] - m);
#pragma unroll
  for (int o = 32; o > 0; o >>= 1) sum += __shfl_down(sum, o);
  if ((tid & 63) == 0) sb[tid >> 6] = sum;
  __syncthreads();
  if (tid == 0) {
    sum = sb[0] + sb[1] + sb[2] + sb[3];
    const float pm = first ? -1e30f : st[row * 3];
    const float ps = first ? 0.f : st[row * 3 + 1];
    const float nm = fmaxf(pm, m);
    st[row * 3] = nm;
    st[row * 3 + 1] = ps * __expf(pm - nm) + sum * __expf(m - nm);
    const int t = y[row];
    const int yc = (t == -100) ? 0 : t;
    const int cl = yc - n0;
    if (cl >= 0 && cl < nC) st[row * 3 + 2] = b2f(lp[cl]);
  }
}

__global__ void zero2(float* p) { p[threadIdx.x] = 0.f; }

__global__ void loss_final(const float* __restrict__ st, const int* __restrict__ y,
                           float* __restrict__ acc)
{
  __shared__ float sb1[4], sb2[4];
  const int tid = threadIdx.x;
  const int row = blockIdx.x * 256 + tid;
  const int t = y[row];
  float nll = 0.f, cv = 0.f;
  if (t != -100) {
    nll = st[row * 3] + __logf(st[row * 3 + 1]) - st[row * 3 + 2];
    cv = 1.f;
  }
#pragma unroll
  for (int o = 32; o > 0; o >>= 1) { nll += __shfl_down(nll, o); cv += __shfl_down(cv, o); }
  if ((tid & 63) == 0) { sb1[tid >> 6] = nll; sb2[tid >> 6] = cv; }
  __syncthreads();
  if (tid == 0) {
    atomicAdd(&acc[0], sb1[0] + sb1[1] + sb1[2] + sb1[3]);
    atomicAdd(&acc[1], sb2[0] + sb2[1] + sb2[2] + sb2[3]);
  }
}
__global__ void loss_write(const float* __restrict__ acc, float* __restrict__ out)
{ out[0] = acc[0] / acc[1]; }

// ---------------- host launcher ----------------
extern "C" void kernel_launch(void* const* d_in, const int* in_sizes, int n_in,
                              void* d_out, int out_size, void* d_ws, size_t ws_size,
                              hipStream_t stream)
{
  const int* x = (const int*)d_in[0];
  const int* y = (const int*)d_in[1];
  const int* s1p = (const int*)d_in[2];
  const float* word = (const float*)d_in[4];
  const float* pos = (const float*)d_in[5];
  const float* typ = (const float*)d_in[6];
  const float* elg = (const float*)d_in[7];
  const float* elb = (const float*)d_in[8];
  const float* Wq = (const float*)d_in[9];
  const float* bq = (const float*)d_in[10];
  const float* Wk = (const float*)d_in[11];
  const float* bk = (const float*)d_in[12];
  const float* Wv = (const float*)d_in[13];
  const float* bvp = (const float*)d_in[14];
  const float* Wo = (const float*)d_in[15];
  const float* bo = (const float*)d_in[16];
  const float* l1g = (const float*)d_in[17];
  const float* l1b = (const float*)d_in[18];
  const float* W1 = (const float*)d_in[19];
  const float* b1 = (const float*)d_in[20];
  const float* W2 = (const float*)d_in[21];
  const float* b2 = (const float*)d_in[22];
  const float* l2g = (const float*)d_in[23];
  const float* l2b = (const float*)d_in[24];
  const float* cW = (const float*)d_in[25];
  const float* cb = (const float*)d_in[26];

  char* base = (char*)d_ws;
  size_t off = 0;
  auto alloc = [&](size_t bytes) -> void* {
    void* p = base + off;
    off = (off + bytes + 255) & ~(size_t)255;
    return p;
  };
  unsigned short* Wqkv = (unsigned short*)alloc(12ull * 2304 * 768 * 2);
  float* bqkv = (float*)alloc(12ull * 2304 * 4);
  unsigned short* Wot = (unsigned short*)alloc(12ull * 768 * 768 * 2);
  unsigned short* W1t = (unsigned short*)alloc(12ull * 3072 * 768 * 2);
  unsigned short* W2t = (unsigned short*)alloc(12ull * 768 * 3072 * 2);
  unsigned short* cWt = (unsigned short*)alloc(21248ull * 768 * 2);
  float* cbp = (float*)alloc(21248ull * 4);
  float* h32 = (float*)alloc(8192ull * 768 * 4);
  unsigned short* hb = (unsigned short*)alloc(8192ull * 768 * 2);
  unsigned short* qkvb = (unsigned short*)alloc(8192ull * 2304 * 2);
  unsigned short* ctxb = (unsigned short*)alloc(8192ull * 768 * 2);
  float* tmp32 = (float*)alloc(8192ull * 768 * 4);
  unsigned short* ffnb = (unsigned short*)alloc(8192ull * 3072 * 2);
  unsigned short* logitb = (unsigned short*)alloc(8192ull * 5376 * 2);
  float* st = (float*)alloc(8192ull * 3 * 4);
  float* acc = (float*)alloc(256);

  const dim3 tt(32, 8);
  transpose_w<<<dim3(24, 24, 12), tt, 0, stream>>>(Wq, Wqkv, 768, 768, 768, 589824, 1769472);
  transpose_w<<<dim3(24, 24, 12), tt, 0, stream>>>(Wk, Wqkv + 589824, 768, 768, 768, 589824, 1769472);
  transpose_w<<<dim3(24, 24, 12), tt, 0, stream>>>(Wv, Wqkv + 1179648, 768, 768, 768, 589824, 1769472);
  transpose_w<<<dim3(24, 24, 12), tt, 0, stream>>>(Wo, Wot, 768, 768, 768, 589824, 589824);
  transpose_w<<<dim3(24, 96, 12), tt, 0, stream>>>(W1, W1t, 768, 3072, 3072, 2359296, 2359296);
  transpose_w<<<dim3(96, 24, 12), tt, 0, stream>>>(W2, W2t, 3072, 768, 768, 2359296, 2359296);
  transpose_w<<<dim3(24, 664, 1), tt, 0, stream>>>(cW, cWt, 768, 21128, 21248, 0, 0);
  build_bqkv<<<108, 256, 0, stream>>>(bq, bk, bvp, bqkv);
  build_clsb<<<83, 256, 0, stream>>>(cb, cbp);
  zero2<<<1, 2, 0, stream>>>(acc);

  embed_kernel<<<8192, 256, 0, stream>>>(x, word, pos, typ, elg, elb, h32, hb);

  for (int l = 0; l < 12; l++) {
    gemm_bf16<<<dim3(64, 18), 256, 0, stream>>>(hb, Wqkv + (long)l * 1769472, bqkv + l * 2304,
                                                nullptr, nullptr, qkvb, 8192, 2304, 768, 2304, 0);
    attn_kernel<<<dim3(4, 12, 32), 256, 0, stream>>>(qkvb, ctxb, s1p);
    gemm_bf16<<<dim3(64, 6), 256, 0, stream>>>(ctxb, Wot + (long)l * 589824, bo + l * 768,
                                               h32, tmp32, nullptr, 8192, 768, 768, 768, 0);
    ln_kernel<<<8192, 256, 0, stream>>>(tmp32, l1g + l * 768, l1b + l * 768, h32, hb);
    gemm_bf16<<<dim3(64, 24), 256, 0, stream>>>(hb, W1t + (long)l * 2359296, b1 + l * 3072,
                                                nullptr, nullptr, ffnb, 8192, 3072, 768, 3072, 1);
    gemm_bf16<<<dim3(64, 6), 256, 0, stream>>>(ffnb, W2t + (long)l * 2359296, b2 + l * 768,
                                               h32, tmp32, nullptr, 8192, 768, 3072, 768, 0);
    ln_kernel<<<8192, 256, 0, stream>>>(tmp32, l2g + l * 768, l2b + l * 768, h32, hb);
  }

  const int n0s[4] = {0, 5376, 10752, 16128};
  const int nCs[4] = {5376, 5376, 5376, 5120};
  for (int c = 0; c < 4; c++) {
    gemm_bf16<<<dim3(64, nCs[c] / 128), 256, 0, stream>>>(hb, cWt + (long)n0s[c] * 768, cbp + n0s[c],
                                                          nullptr, nullptr, logitb,
                                                          8192, nCs[c], 768, nCs[c], 0);
    loss_partial<<<8192, 256, 0, stream>>>(logitb, y, st, n0s[c], nCs[c], c == 0 ? 1 : 0);
  }
  loss_final<<<32, 256, 0, stream>>>(st, y, acc);
  loss_write<<<1, 1, 0, stream>>>(acc, (float*)d_out);
}

// Round 2
// 5983.665 us; speedup vs baseline: 1.3251x; 1.3251x over previous
//
#include <hip/hip_runtime.h>

typedef __attribute__((ext_vector_type(8))) short bf16x8_t;
typedef __attribute__((ext_vector_type(4))) float f32x4_t;
typedef __attribute__((ext_vector_type(4))) int i32x4_t;

__device__ __forceinline__ unsigned short f2b(float f) {
  unsigned int u = __builtin_bit_cast(unsigned int, f);
  u += 0x7fffu + ((u >> 16) & 1u);
  return (unsigned short)(u >> 16);
}
__device__ __forceinline__ float b2f(unsigned short h) {
  unsigned int u = ((unsigned int)h) << 16;
  return __builtin_bit_cast(float, u);
}

// async global->LDS, 16B per lane; LDS dest is wave-uniform base + lane*16
__device__ __forceinline__ void async16(const unsigned short* g, unsigned short* l) {
  __builtin_amdgcn_global_load_lds(
      (const __attribute__((address_space(1))) unsigned int*)g,
      (__attribute__((address_space(3))) unsigned int*)l, 16, 0, 0);
}

// ---------------- transpose+convert: in f32 [K][N] -> out bf16 [Npad][K] ----------------
__global__ void transpose_w(const float* __restrict__ in, unsigned short* __restrict__ out,
                            int K, int N, int Npad, long inBatch, long outBatch)
{
  __shared__ float tile[32][33];
  const int bz = blockIdx.z;
  in += (long)bz * inBatch;
  out += (long)bz * outBatch;
  const int k0 = blockIdx.x * 32, n0 = blockIdx.y * 32;
  const int tx = threadIdx.x, ty = threadIdx.y;  // 32 x 8
#pragma unroll
  for (int i = 0; i < 32; i += 8) {
    const int k = k0 + ty + i, n = n0 + tx;
    tile[ty + i][tx] = (k < K && n < N) ? in[(long)k * N + n] : 0.f;
  }
  __syncthreads();
#pragma unroll
  for (int i = 0; i < 32; i += 8) {
    const int n = n0 + ty + i, k = k0 + tx;
    if (n < Npad && k < K) out[(long)n * K + k] = f2b(tile[tx][ty + i]);
  }
}

__global__ void build_bqkv(const float* __restrict__ bq, const float* __restrict__ bk,
                           const float* __restrict__ bv, float* __restrict__ out)
{
  const int i = blockIdx.x * 256 + threadIdx.x;
  if (i >= 12 * 2304) return;
  const int l = i / 2304, j = i % 2304;
  float v;
  if (j < 768) v = bq[l * 768 + j];
  else if (j < 1536) v = bk[l * 768 + j - 768];
  else v = bv[l * 768 + j - 1536];
  out[i] = v;
}
__global__ void build_clsb(const float* __restrict__ cb, float* __restrict__ out)
{
  const int i = blockIdx.x * 256 + threadIdx.x;
  if (i < 21248) out[i] = (i < 21128) ? cb[i] : 0.f;
}

// ---------------- GEMM: C[M][N] = A[M][K] (bf16) x Bt[N][K] (bf16) ----------------
// async global_load_lds staging with source-side XOR swizzle (conflict-free b128 reads).
// epilogue: +bias[n], gelu (flags&1), +resid (f32), stores Cf (f32) and/or Cb (bf16)
template <int TM, int TN>
__global__ __launch_bounds__(256)
void gemm_as(const unsigned short* __restrict__ A,
             const unsigned short* __restrict__ Bt,
             const float* __restrict__ bias,
             const float* __restrict__ resid,
             float* __restrict__ Cf,
             unsigned short* __restrict__ Cb,
             int K, int ldc, int flags)
{
  constexpr int MT = TM / 32, NT = TN / 32;
  __shared__ unsigned short sh[(TM + TN) * 64];
  unsigned short* lA = sh;
  unsigned short* lB = sh + TM * 64;
  const int tid = threadIdx.x;
  const int wave = tid >> 6, lane = tid & 63;
  const int quad = lane >> 4, lidx = lane & 15;
  const int m0 = blockIdx.x * TM, n0 = blockIdx.y * TN;
  const int wm = (wave >> 1) * (TM / 2), wn = (wave & 1) * (TN / 2);
  f32x4_t acc[MT][NT] = {};
  // staging: each wave covers TM/4 A-rows + TN/4 B-rows in groups of 8 rows (1KB/instr)
  const int r8 = lane >> 3;                 // row within 8-row group
  const int csw = ((lane & 7) ^ r8) * 8;    // swizzled source chunk (elements)
  const unsigned short* ag = A + (long)(m0 + wave * (TM / 4) + r8) * K + csw;
  const unsigned short* bg = Bt + (long)(n0 + wave * (TN / 4) + r8) * K + csw;
  unsigned short* la0 = lA + wave * (TM / 4) * 64;
  unsigned short* lb0 = lB + wave * (TN / 4) * 64;

  for (int k0 = 0; k0 < K; k0 += 64) {
#pragma unroll
    for (int i = 0; i < TM / 32; i++) async16(ag + (long)(i * 8) * K, la0 + i * 512);
#pragma unroll
    for (int i = 0; i < TN / 32; i++) async16(bg + (long)(i * 8) * K, lb0 + i * 512);
    ag += 64; bg += 64;
    __syncthreads();
#pragma unroll
    for (int kk = 0; kk < 2; kk++) {
      bf16x8_t af[MT], bf[NT];
#pragma unroll
      for (int t = 0; t < MT; t++)
        af[t] = *(const bf16x8_t*)&lA[(wm + t * 16 + lidx) * 64 + ((kk * 4 + quad) ^ (lidx & 7)) * 8];
#pragma unroll
      for (int t = 0; t < NT; t++)
        bf[t] = *(const bf16x8_t*)&lB[(wn + t * 16 + lidx) * 64 + ((kk * 4 + quad) ^ (lidx & 7)) * 8];
#pragma unroll
      for (int mt = 0; mt < MT; mt++)
#pragma unroll
        for (int nt = 0; nt < NT; nt++)
          acc[mt][nt] = __builtin_amdgcn_mfma_f32_16x16x32_bf16(af[mt], bf[nt], acc[mt][nt], 0, 0, 0);
    }
    __syncthreads();
  }
#pragma unroll
  for (int mt = 0; mt < MT; mt++) {
#pragma unroll
    for (int nt = 0; nt < NT; nt++) {
#pragma unroll
      for (int r = 0; r < 4; r++) {
        const int row = m0 + wm + mt * 16 + quad * 4 + r;
        const int col = n0 + wn + nt * 16 + lidx;
        float v = acc[mt][nt][r];
        if (bias) v += bias[col];
        if (flags & 1) v = 0.5f * v * (1.0f + erff(v * 0.70710678118f));
        const long o = (long)row * ldc + col;
        if (resid) v += resid[o];
        if (Cf) Cf[o] = v;
        if (Cb) Cb[o] = f2b(v);
      }
    }
  }
}

// ---------------- attention: per (qchunk, head, batch) block ----------------
__global__ __launch_bounds__(256, 2)
void attn_kernel(const unsigned short* __restrict__ qkv,   // [B*S][2304] = Q|K|V
                 unsigned short* __restrict__ ctx,         // [B*S][768]
                 const int* __restrict__ s1p)
{
  __shared__ unsigned short sh[32768];   // 64 KB: K [0,16384), V [16384,32768); P aliases K
  unsigned short* lK = sh;
  unsigned short* lV = sh + 16384;
  unsigned short* lP = sh;
  const int s1 = s1p[0];
  const int qc = blockIdx.x, h = blockIdx.y, b = blockIdx.z;
  const int tid = threadIdx.x;
  const int wave = tid >> 6, lane = tid & 63;
  const int quad = lane >> 4, lidx = lane & 15;
  const long tokbase = (long)b * 256 * 2304 + h * 64;

  {  // stage K,V with xor-swizzled 16B chunks (8 chunks per 64-wide row)
    const int kr = tid >> 3, c8 = tid & 7;
#pragma unroll
    for (int i = 0; i < 8; i++) {
      const int key = kr + i * 32;
      const unsigned short* src = qkv + tokbase + (long)key * 2304 + c8 * 8;
      const int sw = (c8 ^ (key & 7)) << 3;
      *(i32x4_t*)&lK[key * 64 + sw] = *(const i32x4_t*)(src + 768);
      *(i32x4_t*)&lV[key * 64 + sw] = *(const i32x4_t*)(src + 1536);
    }
  }
  bf16x8_t aq[2];
  {
    const int q = qc * 64 + wave * 16 + lidx;
    const unsigned short* qp = qkv + tokbase + (long)q * 2304;
    aq[0] = *(const bf16x8_t*)(qp + quad * 8);
    aq[1] = *(const bf16x8_t*)(qp + 32 + quad * 8);
  }
  __syncthreads();
  // QK^T: scores [16 q rows of this wave] x [256 keys]
  f32x4_t sc[16] = {};
#pragma unroll
  for (int kk = 0; kk < 2; kk++) {
#pragma unroll
    for (int nt = 0; nt < 16; nt++) {
      const int key = nt * 16 + lidx;
      const int ch = kk * 4 + quad;
      bf16x8_t bk = *(const bf16x8_t*)&lK[key * 64 + ((ch ^ (key & 7)) << 3)];
      sc[nt] = __builtin_amdgcn_mfma_f32_16x16x32_bf16(aq[kk], bk, sc[nt], 0, 0, 0);
    }
  }
  __syncthreads();   // all K reads done before P overwrites the same LDS
  const float scale = 0.125f;
  float rsum[4];
#pragma unroll
  for (int r = 0; r < 4; r++) {
    const int ql = wave * 16 + quad * 4 + r;
    const int q = qc * 64 + ql;
    float sv[16], m = -1e30f;
#pragma unroll
    for (int nt = 0; nt < 16; nt++) {
      const int key = nt * 16 + lidx;
      const float s = sc[nt][r] * scale + ((key < s1 || key <= q) ? 0.f : -1e9f);
      sv[nt] = s;
      m = fmaxf(m, s);
    }
#pragma unroll
    for (int o = 1; o < 16; o <<= 1) m = fmaxf(m, __shfl_xor(m, o, 16));
    float sum = 0.f;
#pragma unroll
    for (int nt = 0; nt < 16; nt++) {
      const float p = __expf(sv[nt] - m);
      sum += p;
      const int key = nt * 16 + lidx;
      lP[ql * 256 + ((((key >> 3) ^ (ql & 7))) << 3) + (key & 7)] = f2b(p);
    }
#pragma unroll
    for (int o = 1; o < 16; o <<= 1) sum += __shfl_xor(sum, o, 16);
    rsum[r] = sum;
  }
  __syncthreads();
  // PV: ctx[16 q][64 d] += P[16][256] x V[256][64]
  f32x4_t o4[4] = {};
#pragma unroll
  for (int kk = 0; kk < 8; kk++) {
    const int row = wave * 16 + lidx;
    const int ch = kk * 4 + quad;
    bf16x8_t ap = *(const bf16x8_t*)&lP[row * 256 + ((ch ^ (row & 7)) << 3)];
#pragma unroll
    for (int nt = 0; nt < 4; nt++) {
      bf16x8_t bv;
#pragma unroll
      for (int j = 0; j < 8; j++) {
        const int key = kk * 32 + quad * 8 + j;
        const int d = nt * 16 + lidx;
        bv[j] = (short)lV[key * 64 + (((d >> 3) ^ (key & 7)) << 3) + (d & 7)];
      }
      o4[nt] = __builtin_amdgcn_mfma_f32_16x16x32_bf16(ap, bv, o4[nt], 0, 0, 0);
    }
  }
#pragma unroll
  for (int nt = 0; nt < 4; nt++) {
#pragma unroll
    for (int r = 0; r < 4; r++) {
      const int q = qc * 64 + wave * 16 + quad * 4 + r;
      const int d = nt * 16 + lidx;
      ctx[(long)(b * 256 + q) * 768 + h * 64 + d] = f2b(o4[nt][r] / rsum[r]);
    }
  }
}

// ---------------- LayerNorm over H=768; writes f32 + bf16 ----------------
__global__ void ln_kernel(const float* __restrict__ in, const float* __restrict__ g,
                          const float* __restrict__ be, float* __restrict__ o32,
                          unsigned short* __restrict__ ob)
{
  __shared__ float sb1[4], sb2[4];
  const int row = blockIdx.x, tid = threadIdx.x;
  const float* x = in + (long)row * 768;
  float v[3], s = 0.f, ss = 0.f;
#pragma unroll
  for (int i = 0; i < 3; i++) { v[i] = x[tid + i * 256]; s += v[i]; ss += v[i] * v[i]; }
#pragma unroll
  for (int o = 32; o > 0; o >>= 1) { s += __shfl_down(s, o); ss += __shfl_down(ss, o); }
  if ((tid & 63) == 0) { sb1[tid >> 6] = s; sb2[tid >> 6] = ss; }
  __syncthreads();
  s = sb1[0] + sb1[1] + sb1[2] + sb1[3];
  ss = sb2[0] + sb2[1] + sb2[2] + sb2[3];
  const float mean = s * (1.f / 768.f);
  const float inv = rsqrtf(ss * (1.f / 768.f) - mean * mean + 1e-12f);
#pragma unroll
  for (int i = 0; i < 3; i++) {
    const int c = tid + i * 256;
    const float yv = (v[i] - mean) * inv * g[c] + be[c];
    if (o32) o32[(long)row * 768 + c] = yv;
    ob[(long)row * 768 + c] = f2b(yv);
  }
}

__global__ void embed_kernel(const int* __restrict__ xi, const float* __restrict__ we,
                             const float* __restrict__ pe, const float* __restrict__ te,
                             const float* __restrict__ g, const float* __restrict__ be,
                             float* __restrict__ o32, unsigned short* __restrict__ ob)
{
  __shared__ float sb1[4], sb2[4];
  const int row = blockIdx.x, tid = threadIdx.x;
  const int sidx = row & 255;
  const long id = xi[row];
  float v[3], s = 0.f, ss = 0.f;
#pragma unroll
  for (int i = 0; i < 3; i++) {
    const int c = tid + i * 256;
    v[i] = we[id * 768 + c] + pe[(long)sidx * 768 + c] + te[c];
    s += v[i]; ss += v[i] * v[i];
  }
#pragma unroll
  for (int o = 32; o > 0; o >>= 1) { s += __shfl_down(s, o); ss += __shfl_down(ss, o); }
  if ((tid & 63) == 0) { sb1[tid >> 6] = s; sb2[tid >> 6] = ss; }
  __syncthreads();
  s = sb1[0] + sb1[1] + sb1[2] + sb1[3];
  ss = sb2[0] + sb2[1] + sb2[2] + sb2[3];
  const float mean = s * (1.f / 768.f);
  const float inv = rsqrtf(ss * (1.f / 768.f) - mean * mean + 1e-12f);
#pragma unroll
  for (int i = 0; i < 3; i++) {
    const int c = tid + i * 256;
    const float yv = (v[i] - mean) * inv * g[c] + be[c];
    o32[(long)row * 768 + c] = yv;
    ob[(long)row * 768 + c] = f2b(yv);
  }
}

// ---------------- online log-sum-exp over classifier chunks ----------------
__global__ void loss_partial(const unsigned short* __restrict__ logits,  // [8192][nC] bf16
                             const int* __restrict__ y,
                             float* __restrict__ st,                     // [8192][3]: m, s, target_logit
                             int n0, int nC, int first)
{
  __shared__ float sb[4];
  const int row = blockIdx.x, tid = threadIdx.x;
  const unsigned short* lp = logits + (long)row * nC;
  float lv[21];
  float m = -1e30f;
  int cnt = 0;
#pragma unroll
  for (int i = 0; i < 21; i++) {
    const int c = tid + i * 256;
    if (c < nC) { lv[i] = b2f(lp[c]); m = fmaxf(m, lv[i]); cnt = i + 1; }
  }
#pragma unroll
  for (int o = 32; o > 0; o >>= 1) m = fmaxf(m, __shfl_down(m, o));
  if ((tid & 63) == 0) sb[tid >> 6] = m;
  __syncthreads();
  m = fmaxf(fmaxf(sb[0], sb[1]), fmaxf(sb[2], sb[3]));
  __syncthreads();
  float sum = 0.f;
  for (int i = 0; i < cnt; i++) sum += __expf(lv[i] - m);
#pragma unroll
  for (int o = 32; o > 0; o >>= 1) sum += __shfl_down(sum, o);
  if ((tid & 63) == 0) sb[tid >> 6] = sum;
  __syncthreads();
  if (tid == 0) {
    sum = sb[0] + sb[1] + sb[2] + sb[3];
    const float pm = first ? -1e30f : st[row * 3];
    const float ps = first ? 0.f : st[row * 3 + 1];
    const float nm = fmaxf(pm, m);
    st[row * 3] = nm;
    st[row * 3 + 1] = ps * __expf(pm - nm) + sum * __expf(m - nm);
    const int t = y[row];
    const int yc = (t == -100) ? 0 : t;
    const int cl = yc - n0;
    if (cl >= 0 && cl < nC) st[row * 3 + 2] = b2f(lp[cl]);
  }
}

__global__ void zero2(float* p) { p[threadIdx.x] = 0.f; }

__global__ void loss_final(const float* __restrict__ st, const int* __restrict__ y,
                           float* __restrict__ acc)
{
  __shared__ float sb1[4], sb2[4];
  const int tid = threadIdx.x;
  const int row = blockIdx.x * 256 + tid;
  const int t = y[row];
  float nll = 0.f, cv = 0.f;
  if (t != -100) {
    nll = st[row * 3] + __logf(st[row * 3 + 1]) - st[row * 3 + 2];
    cv = 1.f;
  }
#pragma unroll
  for (int o = 32; o > 0; o >>= 1) { nll += __shfl_down(nll, o); cv += __shfl_down(cv, o); }
  if ((tid & 63) == 0) { sb1[tid >> 6] = nll; sb2[tid >> 6] = cv; }
  __syncthreads();
  if (tid == 0) {
    atomicAdd(&acc[0], sb1[0] + sb1[1] + sb1[2] + sb1[3]);
    atomicAdd(&acc[1], sb2[0] + sb2[1] + sb2[2] + sb2[3]);
  }
}
__global__ void loss_write(const float* __restrict__ acc, float* __restrict__ out)
{ out[0] = acc[0] / acc[1]; }

// ---------------- host launcher ----------------
extern "C" void kernel_launch(void* const* d_in, const int* in_sizes, int n_in,
                              void* d_out, int out_size, void* d_ws, size_t ws_size,
                              hipStream_t stream)
{
  const int* x = (const int*)d_in[0];
  const int* y = (const int*)d_in[1];
  const int* s1p = (const int*)d_in[2];
  const float* word = (const float*)d_in[4];
  const float* pos = (const float*)d_in[5];
  const float* typ = (const float*)d_in[6];
  const float* elg = (const float*)d_in[7];
  const float* elb = (const float*)d_in[8];
  const float* Wq = (const float*)d_in[9];
  const float* bq = (const float*)d_in[10];
  const float* Wk = (const float*)d_in[11];
  const float* bk = (const float*)d_in[12];
  const float* Wv = (const float*)d_in[13];
  const float* bvp = (const float*)d_in[14];
  const float* Wo = (const float*)d_in[15];
  const float* bo = (const float*)d_in[16];
  const float* l1g = (const float*)d_in[17];
  const float* l1b = (const float*)d_in[18];
  const float* W1 = (const float*)d_in[19];
  const float* b1 = (const float*)d_in[20];
  const float* W2 = (const float*)d_in[21];
  const float* b2 = (const float*)d_in[22];
  const float* l2g = (const float*)d_in[23];
  const float* l2b = (const float*)d_in[24];
  const float* cW = (const float*)d_in[25];
  const float* cb = (const float*)d_in[26];

  char* base = (char*)d_ws;
  size_t off = 0;
  auto alloc = [&](size_t bytes) -> void* {
    void* p = base + off;
    off = (off + bytes + 255) & ~(size_t)255;
    return p;
  };
  unsigned short* Wqkv = (unsigned short*)alloc(12ull * 2304 * 768 * 2);
  float* bqkv = (float*)alloc(12ull * 2304 * 4);
  unsigned short* Wot = (unsigned short*)alloc(12ull * 768 * 768 * 2);
  unsigned short* W1t = (unsigned short*)alloc(12ull * 3072 * 768 * 2);
  unsigned short* W2t = (unsigned short*)alloc(12ull * 768 * 3072 * 2);
  unsigned short* cWt = (unsigned short*)alloc(21248ull * 768 * 2);
  float* cbp = (float*)alloc(21248ull * 4);
  float* h32 = (float*)alloc(8192ull * 768 * 4);
  unsigned short* hb = (unsigned short*)alloc(8192ull * 768 * 2);
  unsigned short* qkvb = (unsigned short*)alloc(8192ull * 2304 * 2);
  unsigned short* ctxb = (unsigned short*)alloc(8192ull * 768 * 2);
  float* tmp32 = (float*)alloc(8192ull * 768 * 4);
  unsigned short* ffnb = (unsigned short*)alloc(8192ull * 3072 * 2);
  unsigned short* logitb = (unsigned short*)alloc(8192ull * 5376 * 2);
  float* st = (float*)alloc(8192ull * 3 * 4);
  float* acc = (float*)alloc(256);

  const dim3 tt(32, 8);
  transpose_w<<<dim3(24, 24, 12), tt, 0, stream>>>(Wq, Wqkv, 768, 768, 768, 589824, 1769472);
  transpose_w<<<dim3(24, 24, 12), tt, 0, stream>>>(Wk, Wqkv + 589824, 768, 768, 768, 589824, 1769472);
  transpose_w<<<dim3(24, 24, 12), tt, 0, stream>>>(Wv, Wqkv + 1179648, 768, 768, 768, 589824, 1769472);
  transpose_w<<<dim3(24, 24, 12), tt, 0, stream>>>(Wo, Wot, 768, 768, 768, 589824, 589824);
  transpose_w<<<dim3(24, 96, 12), tt, 0, stream>>>(W1, W1t, 768, 3072, 3072, 2359296, 2359296);
  transpose_w<<<dim3(96, 24, 12), tt, 0, stream>>>(W2, W2t, 3072, 768, 768, 2359296, 2359296);
  transpose_w<<<dim3(24, 664, 1), tt, 0, stream>>>(cW, cWt, 768, 21128, 21248, 0, 0);
  build_bqkv<<<108, 256, 0, stream>>>(bq, bk, bvp, bqkv);
  build_clsb<<<83, 256, 0, stream>>>(cb, cbp);
  zero2<<<1, 2, 0, stream>>>(acc);

  embed_kernel<<<8192, 256, 0, stream>>>(x, word, pos, typ, elg, elb, h32, hb);

  for (int l = 0; l < 12; l++) {
    gemm_as<128, 128><<<dim3(64, 18), 256, 0, stream>>>(hb, Wqkv + (long)l * 1769472, bqkv + l * 2304,
                                                        nullptr, nullptr, qkvb, 768, 2304, 0);
    attn_kernel<<<dim3(4, 12, 32), 256, 0, stream>>>(qkvb, ctxb, s1p);
    gemm_as<64, 128><<<dim3(128, 6), 256, 0, stream>>>(ctxb, Wot + (long)l * 589824, bo + l * 768,
                                                       h32, tmp32, nullptr, 768, 768, 0);
    ln_kernel<<<8192, 256, 0, stream>>>(tmp32, l1g + l * 768, l1b + l * 768, h32, hb);
    gemm_as<128, 128><<<dim3(64, 24), 256, 0, stream>>>(hb, W1t + (long)l * 2359296, b1 + l * 3072,
                                                        nullptr, nullptr, ffnb, 768, 3072, 1);
    gemm_as<64, 128><<<dim3(128, 6), 256, 0, stream>>>(ffnb, W2t + (long)l * 2359296, b2 + l * 768,
                                                       h32, tmp32, nullptr, 3072, 768, 0);
    ln_kernel<<<8192, 256, 0, stream>>>(tmp32, l2g + l * 768, l2b + l * 768, h32, hb);
  }

  const int n0s[4] = {0, 5376, 10752, 16128};
  const int nCs[4] = {5376, 5376, 5376, 5120};
  for (int c = 0; c < 4; c++) {
    gemm_as<128, 128><<<dim3(64, nCs[c] / 128), 256, 0, stream>>>(hb, cWt + (long)n0s[c] * 768, cbp + n0s[c],
                                                                  nullptr, nullptr, logitb,
                                                                  768, nCs[c], 0);
    loss_partial<<<8192, 256, 0, stream>>>(logitb, y, st, n0s[c], nCs[c], c == 0 ? 1 : 0);
  }
  loss_final<<<32, 256, 0, stream>>>(st, y, acc);
  loss_write<<<1, 1, 0, stream>>>(acc, (float*)d_out);
}

// Round 3
// 5358.039 us; speedup vs baseline: 1.4799x; 1.1168x over previous
//
#include <hip/hip_runtime.h>

typedef __attribute__((ext_vector_type(8))) short bf16x8_t;
typedef __attribute__((ext_vector_type(4))) float f32x4_t;
typedef __attribute__((ext_vector_type(4))) int i32x4_t;

#define NPART 332   // total column-half partials for the 21248-col classifier

__device__ __forceinline__ unsigned short f2b(float f) {
  unsigned int u = __builtin_bit_cast(unsigned int, f);
  u += 0x7fffu + ((u >> 16) & 1u);
  return (unsigned short)(u >> 16);
}
__device__ __forceinline__ float b2f(unsigned short h) {
  unsigned int u = ((unsigned int)h) << 16;
  return __builtin_bit_cast(float, u);
}

// async global->LDS, 16B per lane; LDS dest is wave-uniform base + lane*16
__device__ __forceinline__ void async16(const unsigned short* g, unsigned short* l) {
  __builtin_amdgcn_global_load_lds(
      (const __attribute__((address_space(1))) unsigned int*)g,
      (__attribute__((address_space(3))) unsigned int*)l, 16, 0, 0);
}

// ---------------- transpose+convert: in f32 [K][N] -> out bf16 [Npad][K] ----------------
__global__ void transpose_w(const float* __restrict__ in, unsigned short* __restrict__ out,
                            int K, int N, int Npad, long inBatch, long outBatch)
{
  __shared__ float tile[32][33];
  const int bz = blockIdx.z;
  in += (long)bz * inBatch;
  out += (long)bz * outBatch;
  const int k0 = blockIdx.x * 32, n0 = blockIdx.y * 32;
  const int tx = threadIdx.x, ty = threadIdx.y;  // 32 x 8
#pragma unroll
  for (int i = 0; i < 32; i += 8) {
    const int k = k0 + ty + i, n = n0 + tx;
    tile[ty + i][tx] = (k < K && n < N) ? in[(long)k * N + n] : 0.f;
  }
  __syncthreads();
#pragma unroll
  for (int i = 0; i < 32; i += 8) {
    const int n = n0 + ty + i, k = k0 + tx;
    if (n < Npad && k < K) out[(long)n * K + k] = f2b(tile[tx][ty + i]);
  }
}

__global__ void build_bqkv(const float* __restrict__ bq, const float* __restrict__ bk,
                           const float* __restrict__ bv, float* __restrict__ out)
{
  const int i = blockIdx.x * 256 + threadIdx.x;
  if (i >= 12 * 2304) return;
  const int l = i / 2304, j = i % 2304;
  float v;
  if (j < 768) v = bq[l * 768 + j];
  else if (j < 1536) v = bk[l * 768 + j - 768];
  else v = bv[l * 768 + j - 1536];
  out[i] = v;
}
__global__ void build_clsb(const float* __restrict__ cb, float* __restrict__ out)
{
  const int i = blockIdx.x * 256 + threadIdx.x;
  if (i < 21248) out[i] = (i < 21128) ? cb[i] : 0.f;
}

// ---------------- GEMM: C[M][N] = A[M][K] (bf16) x Bt[N][K] (bf16) ----------------
// Double-buffered: one barrier per K-step; async loads for k+1 issued AFTER the
// barrier so the next barrier's vmcnt(0) drain waits on loads that have had a
// full compute phase in flight.
// flags: 1 = gelu, 2 = fused log-sum-exp epilogue (classifier; no C store)
template <int TM, int TN>
__global__ __launch_bounds__(256)
void gemm_db(const unsigned short* __restrict__ A,
             const unsigned short* __restrict__ Bt,
             const float* __restrict__ bias,
             const float* __restrict__ resid,
             float* __restrict__ Cf,
             unsigned short* __restrict__ Cb,
             int K, int ldc, int flags,
             const int* __restrict__ yv, float2* __restrict__ st2,
             float* __restrict__ tgt, int lse_n0)
{
  constexpr int MT = TM / 32, NT = TN / 32;
  constexpr int STRIDE = (TM + TN) * 64;
  __shared__ unsigned short sh[2 * STRIDE];
  const int tid = threadIdx.x;
  const int wave = tid >> 6, lane = tid & 63;
  const int quad = lane >> 4, lidx = lane & 15;
  const int m0 = blockIdx.x * TM, n0 = blockIdx.y * TN;
  const int wm = (wave >> 1) * (TM / 2), wn = (wave & 1) * (TN / 2);
  f32x4_t acc[MT][NT] = {};
  // staging: each wave covers TM/4 A-rows + TN/4 B-rows in groups of 8 rows (1KB/instr)
  const int r8 = lane >> 3;                 // row within 8-row group
  const int csw = ((lane & 7) ^ r8) * 8;    // swizzled source chunk (elements)
  const unsigned short* ag = A + (long)(m0 + wave * (TM / 4) + r8) * K + csw;
  const unsigned short* bg = Bt + (long)(n0 + wave * (TN / 4) + r8) * K + csw;
  const int laOff = wave * (TM / 4) * 64;
  const int lbOff = TM * 64 + wave * (TN / 4) * 64;

  auto issue = [&](int k0, int st) {
    unsigned short* la0 = sh + st * STRIDE + laOff;
    unsigned short* lb0 = sh + st * STRIDE + lbOff;
#pragma unroll
    for (int i = 0; i < TM / 32; i++) async16(ag + (long)(i * 8) * K + k0, la0 + i * 512);
#pragma unroll
    for (int i = 0; i < TN / 32; i++) async16(bg + (long)(i * 8) * K + k0, lb0 + i * 512);
  };

  issue(0, 0);
  int st = 0;
  for (int k0 = 0; k0 < K; k0 += 64, st ^= 1) {
    __syncthreads();                       // drains vmcnt(0): tile k0 ready; prev compute done
    if (k0 + 64 < K) issue(k0 + 64, st ^ 1);
    const unsigned short* lA = sh + st * STRIDE;
    const unsigned short* lB = sh + st * STRIDE + TM * 64;
#pragma unroll
    for (int kk = 0; kk < 2; kk++) {
      bf16x8_t af[MT], bf[NT];
#pragma unroll
      for (int t = 0; t < MT; t++)
        af[t] = *(const bf16x8_t*)&lA[(wm + t * 16 + lidx) * 64 + ((kk * 4 + quad) ^ (lidx & 7)) * 8];
#pragma unroll
      for (int t = 0; t < NT; t++)
        bf[t] = *(const bf16x8_t*)&lB[(wn + t * 16 + lidx) * 64 + ((kk * 4 + quad) ^ (lidx & 7)) * 8];
#pragma unroll
      for (int mt = 0; mt < MT; mt++)
#pragma unroll
        for (int nt = 0; nt < NT; nt++)
          acc[mt][nt] = __builtin_amdgcn_mfma_f32_16x16x32_bf16(af[mt], bf[nt], acc[mt][nt], 0, 0, 0);
    }
  }

  if (flags & 2) {
    // fused log-sum-exp partials: per wave, per row, reduce its 64-col strip
    const int pidx = (lse_n0 >> 6) + blockIdx.y * (TN / 64) + (wave & 1);
#pragma unroll
    for (int mt = 0; mt < MT; mt++) {
#pragma unroll
      for (int r = 0; r < 4; r++) {
        const int row = m0 + wm + mt * 16 + quad * 4 + r;
        float vals[NT], m = -1e30f;
#pragma unroll
        for (int nt = 0; nt < NT; nt++) {
          const int cl = n0 + wn + nt * 16 + lidx;       // chunk-local col
          float v = acc[mt][nt][r] + bias[cl];
          if (lse_n0 + cl >= 21128) v = -1e30f;          // mask pad cols
          vals[nt] = v;
          m = fmaxf(m, v);
        }
#pragma unroll
        for (int o = 1; o < 16; o <<= 1) m = fmaxf(m, __shfl_xor(m, o, 16));
        float s = 0.f;
#pragma unroll
        for (int nt = 0; nt < NT; nt++) s += __expf(vals[nt] - m);
#pragma unroll
        for (int o = 1; o < 16; o <<= 1) s += __shfl_xor(s, o, 16);
        if (lidx == 0) { float2 p; p.x = m; p.y = s; st2[(long)pidx * 8192 + row] = p; }
        const int t = yv[row];
        const int yc = (t == -100) ? 0 : t;
#pragma unroll
        for (int nt = 0; nt < NT; nt++)
          if (lse_n0 + n0 + wn + nt * 16 + lidx == yc) tgt[row] = vals[nt];
      }
    }
    return;
  }

#pragma unroll
  for (int mt = 0; mt < MT; mt++) {
#pragma unroll
    for (int nt = 0; nt < NT; nt++) {
#pragma unroll
      for (int r = 0; r < 4; r++) {
        const int row = m0 + wm + mt * 16 + quad * 4 + r;
        const int col = n0 + wn + nt * 16 + lidx;
        float v = acc[mt][nt][r];
        if (bias) v += bias[col];
        if (flags & 1) v = 0.5f * v * (1.0f + erff(v * 0.70710678118f));
        const long o = (long)row * ldc + col;
        if (resid) v += resid[o];
        if (Cf) Cf[o] = v;
        if (Cb) Cb[o] = f2b(v);
      }
    }
  }
}

// ---------------- attention: per (qchunk, head, batch) block ----------------
__global__ __launch_bounds__(256, 2)
void attn_kernel(const unsigned short* __restrict__ qkv,   // [B*S][2304] = Q|K|V
                 unsigned short* __restrict__ ctx,         // [B*S][768]
                 const int* __restrict__ s1p)
{
  __shared__ unsigned short sh[32768];   // 64 KB: K [0,16384), V [16384,32768); P aliases K
  unsigned short* lK = sh;
  unsigned short* lV = sh + 16384;
  unsigned short* lP = sh;
  const int s1 = s1p[0];
  const int qc = blockIdx.x, h = blockIdx.y, b = blockIdx.z;
  const int tid = threadIdx.x;
  const int wave = tid >> 6, lane = tid & 63;
  const int quad = lane >> 4, lidx = lane & 15;
  const long tokbase = (long)b * 256 * 2304 + h * 64;

  {  // stage K,V with xor-swizzled 16B chunks (8 chunks per 64-wide row)
    const int kr = tid >> 3, c8 = tid & 7;
#pragma unroll
    for (int i = 0; i < 8; i++) {
      const int key = kr + i * 32;
      const unsigned short* src = qkv + tokbase + (long)key * 2304 + c8 * 8;
      const int sw = (c8 ^ (key & 7)) << 3;
      *(i32x4_t*)&lK[key * 64 + sw] = *(const i32x4_t*)(src + 768);
      *(i32x4_t*)&lV[key * 64 + sw] = *(const i32x4_t*)(src + 1536);
    }
  }
  bf16x8_t aq[2];
  {
    const int q = qc * 64 + wave * 16 + lidx;
    const unsigned short* qp = qkv + tokbase + (long)q * 2304;
    aq[0] = *(const bf16x8_t*)(qp + quad * 8);
    aq[1] = *(const bf16x8_t*)(qp + 32 + quad * 8);
  }
  __syncthreads();
  // QK^T: scores [16 q rows of this wave] x [256 keys]
  f32x4_t sc[16] = {};
#pragma unroll
  for (int kk = 0; kk < 2; kk++) {
#pragma unroll
    for (int nt = 0; nt < 16; nt++) {
      const int key = nt * 16 + lidx;
      const int ch = kk * 4 + quad;
      bf16x8_t bk = *(const bf16x8_t*)&lK[key * 64 + ((ch ^ (key & 7)) << 3)];
      sc[nt] = __builtin_amdgcn_mfma_f32_16x16x32_bf16(aq[kk], bk, sc[nt], 0, 0, 0);
    }
  }
  __syncthreads();   // all K reads done before P overwrites the same LDS
  const float scale = 0.125f;
  float rsum[4];
#pragma unroll
  for (int r = 0; r < 4; r++) {
    const int ql = wave * 16 + quad * 4 + r;
    const int q = qc * 64 + ql;
    float sv[16], m = -1e30f;
#pragma unroll
    for (int nt = 0; nt < 16; nt++) {
      const int key = nt * 16 + lidx;
      const float s = sc[nt][r] * scale + ((key < s1 || key <= q) ? 0.f : -1e9f);
      sv[nt] = s;
      m = fmaxf(m, s);
    }
#pragma unroll
    for (int o = 1; o < 16; o <<= 1) m = fmaxf(m, __shfl_xor(m, o, 16));
    float sum = 0.f;
#pragma unroll
    for (int nt = 0; nt < 16; nt++) {
      const float p = __expf(sv[nt] - m);
      sum += p;
      const int key = nt * 16 + lidx;
      lP[ql * 256 + ((((key >> 3) ^ (ql & 7))) << 3) + (key & 7)] = f2b(p);
    }
#pragma unroll
    for (int o = 1; o < 16; o <<= 1) sum += __shfl_xor(sum, o, 16);
    rsum[r] = sum;
  }
  __syncthreads();
  // PV: ctx[16 q][64 d] += P[16][256] x V[256][64]
  f32x4_t o4[4] = {};
#pragma unroll
  for (int kk = 0; kk < 8; kk++) {
    const int row = wave * 16 + lidx;
    const int ch = kk * 4 + quad;
    bf16x8_t ap = *(const bf16x8_t*)&lP[row * 256 + ((ch ^ (row & 7)) << 3)];
#pragma unroll
    for (int nt = 0; nt < 4; nt++) {
      bf16x8_t bv;
#pragma unroll
      for (int j = 0; j < 8; j++) {
        const int key = kk * 32 + quad * 8 + j;
        const int d = nt * 16 + lidx;
        bv[j] = (short)lV[key * 64 + (((d >> 3) ^ (key & 7)) << 3) + (d & 7)];
      }
      o4[nt] = __builtin_amdgcn_mfma_f32_16x16x32_bf16(ap, bv, o4[nt], 0, 0, 0);
    }
  }
#pragma unroll
  for (int nt = 0; nt < 4; nt++) {
#pragma unroll
    for (int r = 0; r < 4; r++) {
      const int q = qc * 64 + wave * 16 + quad * 4 + r;
      const int d = nt * 16 + lidx;
      ctx[(long)(b * 256 + q) * 768 + h * 64 + d] = f2b(o4[nt][r] / rsum[r]);
    }
  }
}

// ---------------- LayerNorm over H=768; writes f32 + bf16 ----------------
__global__ void ln_kernel(const float* __restrict__ in, const float* __restrict__ g,
                          const float* __restrict__ be, float* __restrict__ o32,
                          unsigned short* __restrict__ ob)
{
  __shared__ float sb1[4], sb2[4];
  const int row = blockIdx.x, tid = threadIdx.x;
  const float* x = in + (long)row * 768;
  float v[3], s = 0.f, ss = 0.f;
#pragma unroll
  for (int i = 0; i < 3; i++) { v[i] = x[tid + i * 256]; s += v[i]; ss += v[i] * v[i]; }
#pragma unroll
  for (int o = 32; o > 0; o >>= 1) { s += __shfl_down(s, o); ss += __shfl_down(ss, o); }
  if ((tid & 63) == 0) { sb1[tid >> 6] = s; sb2[tid >> 6] = ss; }
  __syncthreads();
  s = sb1[0] + sb1[1] + sb1[2] + sb1[3];
  ss = sb2[0] + sb2[1] + sb2[2] + sb2[3];
  const float mean = s * (1.f / 768.f);
  const float inv = rsqrtf(ss * (1.f / 768.f) - mean * mean + 1e-12f);
#pragma unroll
  for (int i = 0; i < 3; i++) {
    const int c = tid + i * 256;
    const float yv = (v[i] - mean) * inv * g[c] + be[c];
    if (o32) o32[(long)row * 768 + c] = yv;
    ob[(long)row * 768 + c] = f2b(yv);
  }
}

__global__ void embed_kernel(const int* __restrict__ xi, const float* __restrict__ we,
                             const float* __restrict__ pe, const float* __restrict__ te,
                             const float* __restrict__ g, const float* __restrict__ be,
                             float* __restrict__ o32, unsigned short* __restrict__ ob)
{
  __shared__ float sb1[4], sb2[4];
  const int row = blockIdx.x, tid = threadIdx.x;
  const int sidx = row & 255;
  const long id = xi[row];
  float v[3], s = 0.f, ss = 0.f;
#pragma unroll
  for (int i = 0; i < 3; i++) {
    const int c = tid + i * 256;
    v[i] = we[id * 768 + c] + pe[(long)sidx * 768 + c] + te[c];
    s += v[i]; ss += v[i] * v[i];
  }
#pragma unroll
  for (int o = 32; o > 0; o >>= 1) { s += __shfl_down(s, o); ss += __shfl_down(ss, o); }
  if ((tid & 63) == 0) { sb1[tid >> 6] = s; sb2[tid >> 6] = ss; }
  __syncthreads();
  s = sb1[0] + sb1[1] + sb1[2] + sb1[3];
  ss = sb2[0] + sb2[1] + sb2[2] + sb2[3];
  const float mean = s * (1.f / 768.f);
  const float inv = rsqrtf(ss * (1.f / 768.f) - mean * mean + 1e-12f);
#pragma unroll
  for (int i = 0; i < 3; i++) {
    const int c = tid + i * 256;
    const float yv = (v[i] - mean) * inv * g[c] + be[c];
    o32[(long)row * 768 + c] = yv;
    ob[(long)row * 768 + c] = f2b(yv);
  }
}

__global__ void zero2(float* p) { p[threadIdx.x] = 0.f; }

// merge the NPART per-column-strip (m,s) partials per row, then reduce the loss
__global__ void loss_final2(const float2* __restrict__ st2, const float* __restrict__ tgt,
                            const int* __restrict__ y, float* __restrict__ acc)
{
  __shared__ float sb1[4], sb2[4];
  const int tid = threadIdx.x;
  const int row = blockIdx.x * 256 + tid;
  float m = -1e30f, s = 0.f;
  for (int i = 0; i < NPART; i++) {
    const float2 p = st2[(long)i * 8192 + row];
    if (p.x > m) { s = s * __expf(m - p.x) + p.y; m = p.x; }
    else s += p.y * __expf(p.x - m);
  }
  const int t = y[row];
  float nll = 0.f, cv = 0.f;
  if (t != -100) {
    nll = m + __logf(s) - tgt[row];
    cv = 1.f;
  }
#pragma unroll
  for (int o = 32; o > 0; o >>= 1) { nll += __shfl_down(nll, o); cv += __shfl_down(cv, o); }
  if ((tid & 63) == 0) { sb1[tid >> 6] = nll; sb2[tid >> 6] = cv; }
  __syncthreads();
  if (tid == 0) {
    atomicAdd(&acc[0], sb1[0] + sb1[1] + sb1[2] + sb1[3]);
    atomicAdd(&acc[1], sb2[0] + sb2[1] + sb2[2] + sb2[3]);
  }
}
__global__ void loss_write(const float* __restrict__ acc, float* __restrict__ out)
{ out[0] = acc[0] / acc[1]; }

// ---------------- host launcher ----------------
extern "C" void kernel_launch(void* const* d_in, const int* in_sizes, int n_in,
                              void* d_out, int out_size, void* d_ws, size_t ws_size,
                              hipStream_t stream)
{
  const int* x = (const int*)d_in[0];
  const int* y = (const int*)d_in[1];
  const int* s1p = (const int*)d_in[2];
  const float* word = (const float*)d_in[4];
  const float* pos = (const float*)d_in[5];
  const float* typ = (const float*)d_in[6];
  const float* elg = (const float*)d_in[7];
  const float* elb = (const float*)d_in[8];
  const float* Wq = (const float*)d_in[9];
  const float* bq = (const float*)d_in[10];
  const float* Wk = (const float*)d_in[11];
  const float* bk = (const float*)d_in[12];
  const float* Wv = (const float*)d_in[13];
  const float* bvp = (const float*)d_in[14];
  const float* Wo = (const float*)d_in[15];
  const float* bo = (const float*)d_in[16];
  const float* l1g = (const float*)d_in[17];
  const float* l1b = (const float*)d_in[18];
  const float* W1 = (const float*)d_in[19];
  const float* b1 = (const float*)d_in[20];
  const float* W2 = (const float*)d_in[21];
  const float* b2 = (const float*)d_in[22];
  const float* l2g = (const float*)d_in[23];
  const float* l2b = (const float*)d_in[24];
  const float* cW = (const float*)d_in[25];
  const float* cb = (const float*)d_in[26];

  char* base = (char*)d_ws;
  size_t off = 0;
  auto alloc = [&](size_t bytes) -> void* {
    void* p = base + off;
    off = (off + bytes + 255) & ~(size_t)255;
    return p;
  };
  unsigned short* Wqkv = (unsigned short*)alloc(12ull * 2304 * 768 * 2);
  float* bqkv = (float*)alloc(12ull * 2304 * 4);
  unsigned short* Wot = (unsigned short*)alloc(12ull * 768 * 768 * 2);
  unsigned short* W1t = (unsigned short*)alloc(12ull * 3072 * 768 * 2);
  unsigned short* W2t = (unsigned short*)alloc(12ull * 768 * 3072 * 2);
  unsigned short* cWt = (unsigned short*)alloc(21248ull * 768 * 2);
  float* cbp = (float*)alloc(21248ull * 4);
  float* h32 = (float*)alloc(8192ull * 768 * 4);
  unsigned short* hb = (unsigned short*)alloc(8192ull * 768 * 2);
  unsigned short* qkvb = (unsigned short*)alloc(8192ull * 2304 * 2);
  unsigned short* ctxb = (unsigned short*)alloc(8192ull * 768 * 2);
  float* tmp32 = (float*)alloc(8192ull * 768 * 4);
  unsigned short* ffnb = (unsigned short*)alloc(8192ull * 3072 * 2);
  float2* st2 = (float2*)alloc((size_t)NPART * 8192 * 8);
  float* tgt = (float*)alloc(8192ull * 4);
  float* acc = (float*)alloc(256);

  const dim3 tt(32, 8);
  transpose_w<<<dim3(24, 24, 12), tt, 0, stream>>>(Wq, Wqkv, 768, 768, 768, 589824, 1769472);
  transpose_w<<<dim3(24, 24, 12), tt, 0, stream>>>(Wk, Wqkv + 589824, 768, 768, 768, 589824, 1769472);
  transpose_w<<<dim3(24, 24, 12), tt, 0, stream>>>(Wv, Wqkv + 1179648, 768, 768, 768, 589824, 1769472);
  transpose_w<<<dim3(24, 24, 12), tt, 0, stream>>>(Wo, Wot, 768, 768, 768, 589824, 589824);
  transpose_w<<<dim3(24, 96, 12), tt, 0, stream>>>(W1, W1t, 768, 3072, 3072, 2359296, 2359296);
  transpose_w<<<dim3(96, 24, 12), tt, 0, stream>>>(W2, W2t, 3072, 768, 768, 2359296, 2359296);
  transpose_w<<<dim3(24, 664, 1), tt, 0, stream>>>(cW, cWt, 768, 21128, 21248, 0, 0);
  build_bqkv<<<108, 256, 0, stream>>>(bq, bk, bvp, bqkv);
  build_clsb<<<83, 256, 0, stream>>>(cb, cbp);
  zero2<<<1, 2, 0, stream>>>(acc);

  embed_kernel<<<8192, 256, 0, stream>>>(x, word, pos, typ, elg, elb, h32, hb);

  for (int l = 0; l < 12; l++) {
    gemm_db<128, 128><<<dim3(64, 18), 256, 0, stream>>>(hb, Wqkv + (long)l * 1769472, bqkv + l * 2304,
                                                        nullptr, nullptr, qkvb, 768, 2304, 0,
                                                        nullptr, nullptr, nullptr, 0);
    attn_kernel<<<dim3(4, 12, 32), 256, 0, stream>>>(qkvb, ctxb, s1p);
    gemm_db<64, 128><<<dim3(128, 6), 256, 0, stream>>>(ctxb, Wot + (long)l * 589824, bo + l * 768,
                                                       h32, tmp32, nullptr, 768, 768, 0,
                                                       nullptr, nullptr, nullptr, 0);
    ln_kernel<<<8192, 256, 0, stream>>>(tmp32, l1g + l * 768, l1b + l * 768, h32, hb);
    gemm_db<128, 128><<<dim3(64, 24), 256, 0, stream>>>(hb, W1t + (long)l * 2359296, b1 + l * 3072,
                                                        nullptr, nullptr, ffnb, 768, 3072, 1,
                                                        nullptr, nullptr, nullptr, 0);
    gemm_db<64, 128><<<dim3(128, 6), 256, 0, stream>>>(ffnb, W2t + (long)l * 2359296, b2 + l * 768,
                                                       h32, tmp32, nullptr, 3072, 768, 0,
                                                       nullptr, nullptr, nullptr, 0);
    ln_kernel<<<8192, 256, 0, stream>>>(tmp32, l2g + l * 768, l2b + l * 768, h32, hb);
  }

  const int n0s[4] = {0, 5376, 10752, 16128};
  const int nCs[4] = {5376, 5376, 5376, 5120};
  for (int c = 0; c < 4; c++) {
    gemm_db<128, 128><<<dim3(64, nCs[c] / 128), 256, 0, stream>>>(hb, cWt + (long)n0s[c] * 768, cbp + n0s[c],
                                                                  nullptr, nullptr, nullptr,
                                                                  768, 0, 2, y, st2, tgt, n0s[c]);
  }
  loss_final2<<<32, 256, 0, stream>>>(st2, tgt, y, acc);
  loss_write<<<1, 1, 0, stream>>>(acc, (float*)d_out);
}

// Round 4
// 5285.920 us; speedup vs baseline: 1.5001x; 1.0136x over previous
//
#include <hip/hip_runtime.h>

typedef __attribute__((ext_vector_type(8))) short bf16x8_t;
typedef __attribute__((ext_vector_type(4))) float f32x4_t;
typedef __attribute__((ext_vector_type(4))) int i32x4_t;

#define NPART 332   // 21248/64 column-strip partials for the classifier LSE

__device__ __forceinline__ unsigned short f2b(float f) {
  unsigned int u = __builtin_bit_cast(unsigned int, f);
  u += 0x7fffu + ((u >> 16) & 1u);
  return (unsigned short)(u >> 16);
}
__device__ __forceinline__ float b2f(unsigned short h) {
  unsigned int u = ((unsigned int)h) << 16;
  return __builtin_bit_cast(float, u);
}

// async global->LDS, 16B per lane; LDS dest is wave-uniform base + lane*16
__device__ __forceinline__ void async16(const unsigned short* g, unsigned short* l) {
  __builtin_amdgcn_global_load_lds(
      (const __attribute__((address_space(1))) unsigned int*)g,
      (__attribute__((address_space(3))) unsigned int*)l, 16, 0, 0);
}

// ---------------- transpose+convert: in f32 [K][N] -> out bf16 [Npad][K] ----------------
__global__ void transpose_w(const float* __restrict__ in, unsigned short* __restrict__ out,
                            int K, int N, int Npad, long inBatch, long outBatch)
{
  __shared__ float tile[32][33];
  const int bz = blockIdx.z;
  in += (long)bz * inBatch;
  out += (long)bz * outBatch;
  const int k0 = blockIdx.x * 32, n0 = blockIdx.y * 32;
  const int tx = threadIdx.x, ty = threadIdx.y;  // 32 x 8
#pragma unroll
  for (int i = 0; i < 32; i += 8) {
    const int k = k0 + ty + i, n = n0 + tx;
    tile[ty + i][tx] = (k < K && n < N) ? in[(long)k * N + n] : 0.f;
  }
  __syncthreads();
#pragma unroll
  for (int i = 0; i < 32; i += 8) {
    const int n = n0 + ty + i, k = k0 + tx;
    if (n < Npad && k < K) out[(long)n * K + k] = f2b(tile[tx][ty + i]);
  }
}

__global__ void build_bqkv(const float* __restrict__ bq, const float* __restrict__ bk,
                           const float* __restrict__ bv, float* __restrict__ out)
{
  const int i = blockIdx.x * 256 + threadIdx.x;
  if (i >= 12 * 2304) return;
  const int l = i / 2304, j = i % 2304;
  float v;
  if (j < 768) v = bq[l * 768 + j];
  else if (j < 1536) v = bk[l * 768 + j - 768];
  else v = bv[l * 768 + j - 1536];
  out[i] = v;
}
__global__ void build_clsb(const float* __restrict__ cb, float* __restrict__ out)
{
  const int i = blockIdx.x * 256 + threadIdx.x;
  if (i < 21248) out[i] = (i < 21128) ? cb[i] : 0.f;
}

// ---------------- GEMM: C[M][N] = A[M][K] (bf16) x Bt[N][K] (bf16) ----------------
// Double-buffered, unrolled x2 so stage offsets are compile-time constants
// (LDS reads become base-reg + immediate offset; minimal per-step VALU).
// flags: 1 = gelu, 2 = fused log-sum-exp epilogue (classifier; no C store)
template <int TM, int TN>
__global__ __launch_bounds__(256)
void gemm_db(const unsigned short* __restrict__ A,
             const unsigned short* __restrict__ Bt,
             const float* __restrict__ bias,
             const float* __restrict__ resid,
             float* __restrict__ Cf,
             unsigned short* __restrict__ Cb,
             int K, int ldc, int flags,
             const int* __restrict__ yv, float2* __restrict__ st2,
             float* __restrict__ tgt)
{
  constexpr int MT = TM / 32, NT = TN / 32;
  constexpr int STRIDE = (TM + TN) * 64;
  __shared__ unsigned short sh[2 * STRIDE];
  const int tid = threadIdx.x;
  const int wave = tid >> 6, lane = tid & 63;
  const int quad = lane >> 4, lidx = lane & 15;
  const int m0 = blockIdx.x * TM, n0 = blockIdx.y * TN;
  const int wm = (wave >> 1) * (TM / 2), wn = (wave & 1) * (TN / 2);
  f32x4_t acc[MT][NT] = {};
  // staging: each wave covers TM/4 A-rows + TN/4 B-rows in groups of 8 rows (1KB/instr)
  const int r8 = lane >> 3;                 // row within 8-row group
  const int csw = ((lane & 7) ^ r8) * 8;    // swizzled source chunk (elements)
  const unsigned short* ag = A + (long)(m0 + wave * (TM / 4) + r8) * K + csw;
  const unsigned short* bg = Bt + (long)(n0 + wave * (TN / 4) + r8) * K + csw;
  const int laOff = wave * (TM / 4) * 64;
  const int lbOff = TM * 64 + wave * (TN / 4) * 64;

  auto issue = [&](int k0, int st) {
    unsigned short* la0 = sh + st * STRIDE + laOff;
    unsigned short* lb0 = sh + st * STRIDE + lbOff;
#pragma unroll
    for (int i = 0; i < TM / 32; i++) async16(ag + (long)(i * 8) * K + k0, la0 + i * 512);
#pragma unroll
    for (int i = 0; i < TN / 32; i++) async16(bg + (long)(i * 8) * K + k0, lb0 + i * 512);
  };
  auto compute = [&](int st) {
    const unsigned short* lA = sh + st * STRIDE;
    const unsigned short* lB = lA + TM * 64;
#pragma unroll
    for (int kk = 0; kk < 2; kk++) {
      bf16x8_t af[MT], bf[NT];
#pragma unroll
      for (int t = 0; t < MT; t++)
        af[t] = *(const bf16x8_t*)&lA[(wm + t * 16 + lidx) * 64 + ((kk * 4 + quad) ^ (lidx & 7)) * 8];
#pragma unroll
      for (int t = 0; t < NT; t++)
        bf[t] = *(const bf16x8_t*)&lB[(wn + t * 16 + lidx) * 64 + ((kk * 4 + quad) ^ (lidx & 7)) * 8];
#pragma unroll
      for (int mt = 0; mt < MT; mt++)
#pragma unroll
        for (int nt = 0; nt < NT; nt++)
          acc[mt][nt] = __builtin_amdgcn_mfma_f32_16x16x32_bf16(af[mt], bf[nt], acc[mt][nt], 0, 0, 0);
    }
  };

  issue(0, 0);
  for (int k0 = 0; k0 < K; k0 += 128) {    // K % 128 == 0 for all shapes here
    __syncthreads();                       // vmcnt(0) drain: stage-0 tile ready
    if (k0 + 64 < K) issue(k0 + 64, 1);
    compute(0);
    __syncthreads();                       // stage-1 tile ready
    if (k0 + 128 < K) issue(k0 + 128, 0);
    compute(1);
  }

  if (flags & 2) {
    // fused log-sum-exp partials: per wave, per row, reduce its 64-col strip
    const int pidx = blockIdx.y * 2 + (wave & 1);
#pragma unroll
    for (int mt = 0; mt < MT; mt++) {
#pragma unroll
      for (int r = 0; r < 4; r++) {
        const int row = m0 + wm + mt * 16 + quad * 4 + r;
        float vals[NT], m = -1e30f;
#pragma unroll
        for (int nt = 0; nt < NT; nt++) {
          const int colg = n0 + wn + nt * 16 + lidx;
          float v = acc[mt][nt][r] + bias[colg];
          if (colg >= 21128) v = -1e30f;           // mask pad cols
          vals[nt] = v;
          m = fmaxf(m, v);
        }
#pragma unroll
        for (int o = 1; o < 16; o <<= 1) m = fmaxf(m, __shfl_xor(m, o, 16));
        float s = 0.f;
#pragma unroll
        for (int nt = 0; nt < NT; nt++) s += __expf(vals[nt] - m);
#pragma unroll
        for (int o = 1; o < 16; o <<= 1) s += __shfl_xor(s, o, 16);
        if (lidx == 0) { float2 p; p.x = m; p.y = s; st2[(long)pidx * 8192 + row] = p; }
        const int t = yv[row];
        const int yc = (t == -100) ? 0 : t;
#pragma unroll
        for (int nt = 0; nt < NT; nt++)
          if (n0 + wn + nt * 16 + lidx == yc) tgt[row] = vals[nt];
      }
    }
    return;
  }

#pragma unroll
  for (int mt = 0; mt < MT; mt++) {
#pragma unroll
    for (int nt = 0; nt < NT; nt++) {
#pragma unroll
      for (int r = 0; r < 4; r++) {
        const int row = m0 + wm + mt * 16 + quad * 4 + r;
        const int col = n0 + wn + nt * 16 + lidx;
        float v = acc[mt][nt][r];
        if (bias) v += bias[col];
        if (flags & 1) v = 0.5f * v * (1.0f + erff(v * 0.70710678118f));
        const long o = (long)row * ldc + col;
        if (resid) v += resid[o];
        if (Cf) Cf[o] = v;
        if (Cb) Cb[o] = f2b(v);
      }
    }
  }
}

// ---------------- attention: per (qchunk, head, batch) block ----------------
__global__ __launch_bounds__(256, 2)
void attn_kernel(const unsigned short* __restrict__ qkv,   // [B*S][2304] = Q|K|V
                 unsigned short* __restrict__ ctx,         // [B*S][768]
                 const int* __restrict__ s1p)
{
  __shared__ unsigned short sh[32768];   // 64 KB: K [0,16384), V [16384,32768); P aliases K
  unsigned short* lK = sh;
  unsigned short* lV = sh + 16384;
  unsigned short* lP = sh;
  const int s1 = s1p[0];
  const int qc = blockIdx.x, h = blockIdx.y, b = blockIdx.z;
  const int tid = threadIdx.x;
  const int wave = tid >> 6, lane = tid & 63;
  const int quad = lane >> 4, lidx = lane & 15;
  const long tokbase = (long)b * 256 * 2304 + h * 64;

  {  // stage K,V with xor-swizzled 16B chunks (8 chunks per 64-wide row)
    const int kr = tid >> 3, c8 = tid & 7;
#pragma unroll
    for (int i = 0; i < 8; i++) {
      const int key = kr + i * 32;
      const unsigned short* src = qkv + tokbase + (long)key * 2304 + c8 * 8;
      const int sw = (c8 ^ (key & 7)) << 3;
      *(i32x4_t*)&lK[key * 64 + sw] = *(const i32x4_t*)(src + 768);
      *(i32x4_t*)&lV[key * 64 + sw] = *(const i32x4_t*)(src + 1536);
    }
  }
  bf16x8_t aq[2];
  {
    const int q = qc * 64 + wave * 16 + lidx;
    const unsigned short* qp = qkv + tokbase + (long)q * 2304;
    aq[0] = *(const bf16x8_t*)(qp + quad * 8);
    aq[1] = *(const bf16x8_t*)(qp + 32 + quad * 8);
  }
  __syncthreads();
  // QK^T: scores [16 q rows of this wave] x [256 keys]
  f32x4_t sc[16] = {};
#pragma unroll
  for (int kk = 0; kk < 2; kk++) {
#pragma unroll
    for (int nt = 0; nt < 16; nt++) {
      const int key = nt * 16 + lidx;
      const int ch = kk * 4 + quad;
      bf16x8_t bk = *(const bf16x8_t*)&lK[key * 64 + ((ch ^ (key & 7)) << 3)];
      sc[nt] = __builtin_amdgcn_mfma_f32_16x16x32_bf16(aq[kk], bk, sc[nt], 0, 0, 0);
    }
  }
  __syncthreads();   // all K reads done before P overwrites the same LDS
  const float scale = 0.125f;
  float rsum[4];
#pragma unroll
  for (int r = 0; r < 4; r++) {
    const int ql = wave * 16 + quad * 4 + r;
    const int q = qc * 64 + ql;
    float sv[16], m = -1e30f;
#pragma unroll
    for (int nt = 0; nt < 16; nt++) {
      const int key = nt * 16 + lidx;
      const float s = sc[nt][r] * scale + ((key < s1 || key <= q) ? 0.f : -1e9f);
      sv[nt] = s;
      m = fmaxf(m, s);
    }
#pragma unroll
    for (int o = 1; o < 16; o <<= 1) m = fmaxf(m, __shfl_xor(m, o, 16));
    float sum = 0.f;
#pragma unroll
    for (int nt = 0; nt < 16; nt++) {
      const float p = __expf(sv[nt] - m);
      sum += p;
      const int key = nt * 16 + lidx;
      lP[ql * 256 + ((((key >> 3) ^ (ql & 7))) << 3) + (key & 7)] = f2b(p);
    }
#pragma unroll
    for (int o = 1; o < 16; o <<= 1) sum += __shfl_xor(sum, o, 16);
    rsum[r] = sum;
  }
  __syncthreads();
  // PV: ctx[16 q][64 d] += P[16][256] x V[256][64]
  f32x4_t o4[4] = {};
#pragma unroll
  for (int kk = 0; kk < 8; kk++) {
    const int row = wave * 16 + lidx;
    const int ch = kk * 4 + quad;
    bf16x8_t ap = *(const bf16x8_t*)&lP[row * 256 + ((ch ^ (row & 7)) << 3)];
#pragma unroll
    for (int nt = 0; nt < 4; nt++) {
      bf16x8_t bv;
#pragma unroll
      for (int j = 0; j < 8; j++) {
        const int key = kk * 32 + quad * 8 + j;
        const int d = nt * 16 + lidx;
        bv[j] = (short)lV[key * 64 + (((d >> 3) ^ (key & 7)) << 3) + (d & 7)];
      }
      o4[nt] = __builtin_amdgcn_mfma_f32_16x16x32_bf16(ap, bv, o4[nt], 0, 0, 0);
    }
  }
#pragma unroll
  for (int nt = 0; nt < 4; nt++) {
#pragma unroll
    for (int r = 0; r < 4; r++) {
      const int q = qc * 64 + wave * 16 + quad * 4 + r;
      const int d = nt * 16 + lidx;
      ctx[(long)(b * 256 + q) * 768 + h * 64 + d] = f2b(o4[nt][r] / rsum[r]);
    }
  }
}

// ---------------- LayerNorm over H=768; writes f32 + bf16 ----------------
__global__ void ln_kernel(const float* __restrict__ in, const float* __restrict__ g,
                          const float* __restrict__ be, float* __restrict__ o32,
                          unsigned short* __restrict__ ob)
{
  __shared__ float sb1[4], sb2[4];
  const int row = blockIdx.x, tid = threadIdx.x;
  const float* x = in + (long)row * 768;
  float v[3], s = 0.f, ss = 0.f;
#pragma unroll
  for (int i = 0; i < 3; i++) { v[i] = x[tid + i * 256]; s += v[i]; ss += v[i] * v[i]; }
#pragma unroll
  for (int o = 32; o > 0; o >>= 1) { s += __shfl_down(s, o); ss += __shfl_down(ss, o); }
  if ((tid & 63) == 0) { sb1[tid >> 6] = s; sb2[tid >> 6] = ss; }
  __syncthreads();
  s = sb1[0] + sb1[1] + sb1[2] + sb1[3];
  ss = sb2[0] + sb2[1] + sb2[2] + sb2[3];
  const float mean = s * (1.f / 768.f);
  const float inv = rsqrtf(ss * (1.f / 768.f) - mean * mean + 1e-12f);
#pragma unroll
  for (int i = 0; i < 3; i++) {
    const int c = tid + i * 256;
    const float yv = (v[i] - mean) * inv * g[c] + be[c];
    if (o32) o32[(long)row * 768 + c] = yv;
    ob[(long)row * 768 + c] = f2b(yv);
  }
}

__global__ void embed_kernel(const int* __restrict__ xi, const float* __restrict__ we,
                             const float* __restrict__ pe, const float* __restrict__ te,
                             const float* __restrict__ g, const float* __restrict__ be,
                             float* __restrict__ o32, unsigned short* __restrict__ ob)
{
  __shared__ float sb1[4], sb2[4];
  const int row = blockIdx.x, tid = threadIdx.x;
  const int sidx = row & 255;
  const long id = xi[row];
  float v[3], s = 0.f, ss = 0.f;
#pragma unroll
  for (int i = 0; i < 3; i++) {
    const int c = tid + i * 256;
    v[i] = we[id * 768 + c] + pe[(long)sidx * 768 + c] + te[c];
    s += v[i]; ss += v[i] * v[i];
  }
#pragma unroll
  for (int o = 32; o > 0; o >>= 1) { s += __shfl_down(s, o); ss += __shfl_down(ss, o); }
  if ((tid & 63) == 0) { sb1[tid >> 6] = s; sb2[tid >> 6] = ss; }
  __syncthreads();
  s = sb1[0] + sb1[1] + sb1[2] + sb1[3];
  ss = sb2[0] + sb2[1] + sb2[2] + sb2[3];
  const float mean = s * (1.f / 768.f);
  const float inv = rsqrtf(ss * (1.f / 768.f) - mean * mean + 1e-12f);
#pragma unroll
  for (int i = 0; i < 3; i++) {
    const int c = tid + i * 256;
    const float yv = (v[i] - mean) * inv * g[c] + be[c];
    o32[(long)row * 768 + c] = yv;
    ob[(long)row * 768 + c] = f2b(yv);
  }
}

__global__ void zero2(float* p) { p[threadIdx.x] = 0.f; }

// merge the NPART per-column-strip (m,s) partials per row, then reduce the loss
__global__ void loss_final2(const float2* __restrict__ st2, const float* __restrict__ tgt,
                            const int* __restrict__ y, float* __restrict__ acc)
{
  __shared__ float sb1[4], sb2[4];
  const int tid = threadIdx.x;
  const int row = blockIdx.x * 256 + tid;
  float m = -1e30f, s = 0.f;
  for (int i = 0; i < NPART; i++) {
    const float2 p = st2[(long)i * 8192 + row];
    if (p.x > m) { s = s * __expf(m - p.x) + p.y; m = p.x; }
    else s += p.y * __expf(p.x - m);
  }
  const int t = y[row];
  float nll = 0.f, cv = 0.f;
  if (t != -100) {
    nll = m + __logf(s) - tgt[row];
    cv = 1.f;
  }
#pragma unroll
  for (int o = 32; o > 0; o >>= 1) { nll += __shfl_down(nll, o); cv += __shfl_down(cv, o); }
  if ((tid & 63) == 0) { sb1[tid >> 6] = nll; sb2[tid >> 6] = cv; }
  __syncthreads();
  if (tid == 0) {
    atomicAdd(&acc[0], sb1[0] + sb1[1] + sb1[2] + sb1[3]);
    atomicAdd(&acc[1], sb2[0] + sb2[1] + sb2[2] + sb2[3]);
  }
}
__global__ void loss_write(const float* __restrict__ acc, float* __restrict__ out)
{ out[0] = acc[0] / acc[1]; }

// ---------------- host launcher ----------------
extern "C" void kernel_launch(void* const* d_in, const int* in_sizes, int n_in,
                              void* d_out, int out_size, void* d_ws, size_t ws_size,
                              hipStream_t stream)
{
  const int* x = (const int*)d_in[0];
  const int* y = (const int*)d_in[1];
  const int* s1p = (const int*)d_in[2];
  const float* word = (const float*)d_in[4];
  const float* pos = (const float*)d_in[5];
  const float* typ = (const float*)d_in[6];
  const float* elg = (const float*)d_in[7];
  const float* elb = (const float*)d_in[8];
  const float* Wq = (const float*)d_in[9];
  const float* bq = (const float*)d_in[10];
  const float* Wk = (const float*)d_in[11];
  const float* bk = (const float*)d_in[12];
  const float* Wv = (const float*)d_in[13];
  const float* bvp = (const float*)d_in[14];
  const float* Wo = (const float*)d_in[15];
  const float* bo = (const float*)d_in[16];
  const float* l1g = (const float*)d_in[17];
  const float* l1b = (const float*)d_in[18];
  const float* W1 = (const float*)d_in[19];
  const float* b1 = (const float*)d_in[20];
  const float* W2 = (const float*)d_in[21];
  const float* b2 = (const float*)d_in[22];
  const float* l2g = (const float*)d_in[23];
  const float* l2b = (const float*)d_in[24];
  const float* cW = (const float*)d_in[25];
  const float* cb = (const float*)d_in[26];

  char* base = (char*)d_ws;
  size_t off = 0;
  auto alloc = [&](size_t bytes) -> void* {
    void* p = base + off;
    off = (off + bytes + 255) & ~(size_t)255;
    return p;
  };
  unsigned short* Wqkv = (unsigned short*)alloc(12ull * 2304 * 768 * 2);
  float* bqkv = (float*)alloc(12ull * 2304 * 4);
  unsigned short* Wot = (unsigned short*)alloc(12ull * 768 * 768 * 2);
  unsigned short* W1t = (unsigned short*)alloc(12ull * 3072 * 768 * 2);
  unsigned short* W2t = (unsigned short*)alloc(12ull * 768 * 3072 * 2);
  unsigned short* cWt = (unsigned short*)alloc(21248ull * 768 * 2);
  float* cbp = (float*)alloc(21248ull * 4);
  float* h32 = (float*)alloc(8192ull * 768 * 4);
  unsigned short* hb = (unsigned short*)alloc(8192ull * 768 * 2);
  unsigned short* qkvb = (unsigned short*)alloc(8192ull * 2304 * 2);
  unsigned short* ctxb = (unsigned short*)alloc(8192ull * 768 * 2);
  float* tmp32 = (float*)alloc(8192ull * 768 * 4);
  unsigned short* ffnb = (unsigned short*)alloc(8192ull * 3072 * 2);
  float2* st2 = (float2*)alloc((size_t)NPART * 8192 * 8);
  float* tgt = (float*)alloc(8192ull * 4);
  float* acc = (float*)alloc(256);

  const dim3 tt(32, 8);
  transpose_w<<<dim3(24, 24, 12), tt, 0, stream>>>(Wq, Wqkv, 768, 768, 768, 589824, 1769472);
  transpose_w<<<dim3(24, 24, 12), tt, 0, stream>>>(Wk, Wqkv + 589824, 768, 768, 768, 589824, 1769472);
  transpose_w<<<dim3(24, 24, 12), tt, 0, stream>>>(Wv, Wqkv + 1179648, 768, 768, 768, 589824, 1769472);
  transpose_w<<<dim3(24, 24, 12), tt, 0, stream>>>(Wo, Wot, 768, 768, 768, 589824, 589824);
  transpose_w<<<dim3(24, 96, 12), tt, 0, stream>>>(W1, W1t, 768, 3072, 3072, 2359296, 2359296);
  transpose_w<<<dim3(96, 24, 12), tt, 0, stream>>>(W2, W2t, 3072, 768, 768, 2359296, 2359296);
  transpose_w<<<dim3(24, 664, 1), tt, 0, stream>>>(cW, cWt, 768, 21128, 21248, 0, 0);
  build_bqkv<<<108, 256, 0, stream>>>(bq, bk, bvp, bqkv);
  build_clsb<<<83, 256, 0, stream>>>(cb, cbp);
  zero2<<<1, 2, 0, stream>>>(acc);

  embed_kernel<<<8192, 256, 0, stream>>>(x, word, pos, typ, elg, elb, h32, hb);

  for (int l = 0; l < 12; l++) {
    gemm_db<128, 128><<<dim3(64, 18), 256, 0, stream>>>(hb, Wqkv + (long)l * 1769472, bqkv + l * 2304,
                                                        nullptr, nullptr, qkvb, 768, 2304, 0,
                                                        nullptr, nullptr, nullptr);
    attn_kernel<<<dim3(4, 12, 32), 256, 0, stream>>>(qkvb, ctxb, s1p);
    gemm_db<64, 128><<<dim3(128, 6), 256, 0, stream>>>(ctxb, Wot + (long)l * 589824, bo + l * 768,
                                                       h32, tmp32, nullptr, 768, 768, 0,
                                                       nullptr, nullptr, nullptr);
    ln_kernel<<<8192, 256, 0, stream>>>(tmp32, l1g + l * 768, l1b + l * 768, h32, hb);
    gemm_db<128, 128><<<dim3(64, 24), 256, 0, stream>>>(hb, W1t + (long)l * 2359296, b1 + l * 3072,
                                                        nullptr, nullptr, ffnb, 768, 3072, 1,
                                                        nullptr, nullptr, nullptr);
    gemm_db<64, 128><<<dim3(128, 6), 256, 0, stream>>>(ffnb, W2t + (long)l * 2359296, b2 + l * 768,
                                                       h32, tmp32, nullptr, 3072, 768, 0,
                                                       nullptr, nullptr, nullptr);
    ln_kernel<<<8192, 256, 0, stream>>>(tmp32, l2g + l * 768, l2b + l * 768, h32, hb);
  }

  // classifier + fused LSE: one dispatch over all 21248 (padded) columns
  gemm_db<128, 128><<<dim3(64, 166), 256, 0, stream>>>(hb, cWt, cbp,
                                                       nullptr, nullptr, nullptr,
                                                       768, 0, 2, y, st2, tgt);
  loss_final2<<<32, 256, 0, stream>>>(st2, tgt, y, acc);
  loss_write<<<1, 1, 0, stream>>>(acc, (float*)d_out);
}